// Round 1
// baseline (2351.290 us; speedup 1.0000x reference)
//
#include <hip/hip_runtime.h>
#include <math.h>

// Problem dims (fixed by setup_inputs)
constexpr int Bn = 32;    // batch
constexpr int Tn = 2048;  // time
constexpr int Hn = 1024;  // decoder hidden
constexpr int An = 512;   // attention dim
constexpr int En = 2048;  // enc_dim = 2*H
// rows of the big GEMM = Bn*Tn = 65536

// ---------------------------------------------------------------------------
// K1: query[b,a] = relu(sum_h dec[b,h] * Wq[a,h] + bq[a])
// grid (32, 4), block 128  -> a = blockIdx.y*128 + tid
// ---------------------------------------------------------------------------
__global__ void query_kernel(const float* __restrict__ dec,
                             const float* __restrict__ Wq,
                             const float* __restrict__ bq,
                             float* __restrict__ qbuf) {
  __shared__ float sdec[Hn];
  const int b = blockIdx.x;
  for (int i = threadIdx.x; i < Hn; i += blockDim.x) sdec[i] = dec[b * Hn + i];
  __syncthreads();
  const int a = blockIdx.y * 128 + threadIdx.x;
  const float* w = Wq + (size_t)a * Hn;
  float acc = 0.f;
  #pragma unroll 4
  for (int k = 0; k < Hn; k += 4) {
    float4 wv = *(const float4*)(w + k);
    acc = fmaf(wv.x, sdec[k + 0], acc);
    acc = fmaf(wv.y, sdec[k + 1], acc);
    acc = fmaf(wv.z, sdec[k + 2], acc);
    acc = fmaf(wv.w, sdec[k + 3], acc);
  }
  qbuf[b * An + a] = fmaxf(acc + bq[a], 0.f);
}

// ---------------------------------------------------------------------------
// K2: energy[row] = sum_a relu( sum_e enc[row,e]*Wk[a,e] + bk[a] ) * q[b,a]
// Tiled fp32 GEMM fused with relu+dot(q). Tile: 32 rows x 512 a, BK=16.
// 256 threads: c = tid&63 (64 col-lanes), r = tid>>6 (4 row-groups of 8 rows).
// Each thread: 8 rows x 8 cols accumulators. Each wave owns rows r*8..r*8+7
// and all 512 cols -> epilogue is a pure in-wave shuffle reduction.
// ---------------------------------------------------------------------------
__global__ __launch_bounds__(256, 2)
void energy_kernel(const float* __restrict__ enc,
                   const float* __restrict__ Wk,
                   const float* __restrict__ bk,
                   const float* __restrict__ qbuf,
                   float* __restrict__ energy) {
  __shared__ float sA[16][36];   // [kk][row], +4 pad spreads staging-write banks
  __shared__ float sB[16][516];  // [kk][a],  +4 pad (keeps 16B alignment of rows)

  const int tid = threadIdx.x;
  const int c = tid & 63;
  const int r = tid >> 6;
  const long row_base = (long)blockIdx.x * 32;
  const int bidx = (int)(row_base >> 11);  // row_base / Tn (tiles never cross b)

  float acc[8][8];
  #pragma unroll
  for (int i = 0; i < 8; ++i)
    #pragma unroll
    for (int j = 0; j < 8; ++j) acc[i][j] = 0.f;

  for (int k0 = 0; k0 < En; k0 += 16) {
    // stage A: 32 rows x 16 k = 128 float4 (threads 0..127)
    if (tid < 128) {
      const int rown = tid >> 2;
      const int kk4 = (tid & 3) * 4;
      float4 v = *(const float4*)(enc + (row_base + rown) * (long)En + k0 + kk4);
      sA[kk4 + 0][rown] = v.x;
      sA[kk4 + 1][rown] = v.y;
      sA[kk4 + 2][rown] = v.z;
      sA[kk4 + 3][rown] = v.w;
    }
    // stage B: 512 a x 16 k = 2048 float4, 8 per thread
    #pragma unroll
    for (int it = 0; it < 8; ++it) {
      const int lin = tid + 256 * it;      // 0..2047
      const int a = lin >> 2;
      const int kk4 = (lin & 3) * 4;
      float4 v = *(const float4*)(Wk + (size_t)a * En + k0 + kk4);
      sB[kk4 + 0][a] = v.x;
      sB[kk4 + 1][a] = v.y;
      sB[kk4 + 2][a] = v.z;
      sB[kk4 + 3][a] = v.w;
    }
    __syncthreads();

    #pragma unroll
    for (int kk = 0; kk < 16; ++kk) {
      float av[8], bv[8];
      #pragma unroll
      for (int i = 0; i < 8; ++i) av[i] = sA[kk][r * 8 + i];      // wave-broadcast
      #pragma unroll
      for (int j = 0; j < 4; ++j) bv[j] = sB[kk][c * 4 + j];       // contiguous
      #pragma unroll
      for (int j = 0; j < 4; ++j) bv[4 + j] = sB[kk][256 + c * 4 + j];
      #pragma unroll
      for (int i = 0; i < 8; ++i)
        #pragma unroll
        for (int j = 0; j < 8; ++j) acc[i][j] = fmaf(av[i], bv[j], acc[i][j]);
    }
    __syncthreads();
  }

  // epilogue: bias + relu + weight by q, reduce over a within the wave
  int aj[8];
  #pragma unroll
  for (int j = 0; j < 4; ++j) { aj[j] = c * 4 + j; aj[4 + j] = 256 + c * 4 + j; }
  float qv[8], bb[8];
  #pragma unroll
  for (int j = 0; j < 8; ++j) {
    qv[j] = qbuf[bidx * An + aj[j]];
    bb[j] = bk[aj[j]];
  }
  float part[8];
  #pragma unroll
  for (int i = 0; i < 8; ++i) {
    float s = 0.f;
    #pragma unroll
    for (int j = 0; j < 8; ++j)
      s = fmaf(fmaxf(acc[i][j] + bb[j], 0.f), qv[j], s);
    part[i] = s;
  }
  #pragma unroll
  for (int off = 32; off > 0; off >>= 1) {
    #pragma unroll
    for (int i = 0; i < 8; ++i) part[i] += __shfl_down(part[i], off, 64);
  }
  if (c == 0) {
    #pragma unroll
    for (int i = 0; i < 8; ++i) energy[row_base + r * 8 + i] = part[i];
  }
}

// ---------------------------------------------------------------------------
// K3: in-place softmax over T with mask renorm; also zeroes the context slot
// (needed for K4's atomics). att = p*mask / sum(p*mask), p = exp(e - max).
// grid 32 (one block per b), block 256.
// ---------------------------------------------------------------------------
__global__ void softmax_kernel(float* __restrict__ att,     // in: energy, out: attention
                               const float* __restrict__ mask,
                               float* __restrict__ ctx) {
  const int b = blockIdx.x;
  const int tid = threadIdx.x;
  const int lane = tid & 63;
  const int wave = tid >> 6;
  __shared__ float wred[4];

  // zero context slot for K4's atomicAdd
  for (int i = tid; i < En; i += 256) ctx[b * En + i] = 0.f;

  float e[8];
  float m = -INFINITY;
  #pragma unroll
  for (int i = 0; i < 8; ++i) {
    e[i] = att[b * Tn + tid + i * 256];
    m = fmaxf(m, e[i]);
  }
  #pragma unroll
  for (int off = 32; off > 0; off >>= 1) m = fmaxf(m, __shfl_xor(m, off, 64));
  if (lane == 0) wred[wave] = m;
  __syncthreads();
  m = fmaxf(fmaxf(wred[0], wred[1]), fmaxf(wred[2], wred[3]));
  __syncthreads();

  float p[8];
  float s = 0.f;
  #pragma unroll
  for (int i = 0; i < 8; ++i) {
    p[i] = expf(e[i] - m) * mask[b * Tn + tid + i * 256];
    s += p[i];
  }
  #pragma unroll
  for (int off = 32; off > 0; off >>= 1) s += __shfl_xor(s, off, 64);
  if (lane == 0) wred[wave] = s;
  __syncthreads();
  const float inv = 1.f / (wred[0] + wred[1] + wred[2] + wred[3]);
  #pragma unroll
  for (int i = 0; i < 8; ++i) att[b * Tn + tid + i * 256] = p[i] * inv;
}

// ---------------------------------------------------------------------------
// K4: context[b,e] = sum_t att[b,t] * enc[b,t,e]  (memory-bound, 512 MB read)
// grid 512 = (b:32) x (echunk:2) x (tseg:8); block 256, float4/thread.
// Partial t-segments accumulated with atomicAdd (ctx zeroed in K3).
// ---------------------------------------------------------------------------
__global__ void context_kernel(const float* __restrict__ enc,
                               const float* __restrict__ att,
                               float* __restrict__ ctx) {
  const int bid = blockIdx.x;
  const int b = bid >> 4;
  const int echunk = (bid >> 3) & 1;
  const int tseg = bid & 7;
  const int tid = threadIdx.x;
  const int e0 = echunk * 1024 + tid * 4;
  const int t0 = tseg * 256;

  __shared__ float satt[256];
  satt[tid] = att[b * Tn + t0 + tid];
  __syncthreads();

  const float* base = enc + ((size_t)(b * Tn + t0)) * En + e0;
  float4 acc = make_float4(0.f, 0.f, 0.f, 0.f);
  #pragma unroll 8
  for (int t = 0; t < 256; ++t) {
    const float w = satt[t];
    float4 v = *(const float4*)(base + (size_t)t * En);
    acc.x = fmaf(w, v.x, acc.x);
    acc.y = fmaf(w, v.y, acc.y);
    acc.z = fmaf(w, v.z, acc.z);
    acc.w = fmaf(w, v.w, acc.w);
  }
  atomicAdd(&ctx[b * En + e0 + 0], acc.x);
  atomicAdd(&ctx[b * En + e0 + 1], acc.y);
  atomicAdd(&ctx[b * En + e0 + 2], acc.z);
  atomicAdd(&ctx[b * En + e0 + 3], acc.w);
}

// ---------------------------------------------------------------------------
extern "C" void kernel_launch(void* const* d_in, const int* in_sizes, int n_in,
                              void* d_out, int out_size, void* d_ws, size_t ws_size,
                              hipStream_t stream) {
  const float* enc  = (const float*)d_in[0];  // [B,T,En]
  const float* dec  = (const float*)d_in[1];  // [B,H]
  const float* mask = (const float*)d_in[2];  // [B,1,T]
  const float* Wq   = (const float*)d_in[3];  // [A,H]
  const float* bq   = (const float*)d_in[4];  // [A]
  const float* Wk   = (const float*)d_in[5];  // [A,En]
  const float* bk   = (const float*)d_in[6];  // [A]

  float* out = (float*)d_out;
  float* att = out;                 // output 0: attention [B,1,T]  (65536)
  float* ctx = out + Bn * Tn;       // output 1: context  [B,En]    (65536)
  float* qbuf = ctx;                // stash query (16384 floats) in ctx slot;
                                    // dead after K2, K3 zeroes the slot.

  query_kernel<<<dim3(Bn, 4), 128, 0, stream>>>(dec, Wq, bq, qbuf);
  energy_kernel<<<(Bn * Tn) / 32, 256, 0, stream>>>(enc, Wk, bk, qbuf, att);
  softmax_kernel<<<Bn, 256, 0, stream>>>(att, mask, ctx);
  context_kernel<<<Bn * 2 * 8, 256, 0, stream>>>(enc, att, ctx);
}

// Round 2
// 1196.906 us; speedup vs baseline: 1.9645x; 1.9645x over previous
//
#include <hip/hip_runtime.h>
#include <math.h>

// Problem dims (fixed by setup_inputs)
constexpr int Bn = 32;    // batch
constexpr int Tn = 2048;  // time
constexpr int Hn = 1024;  // decoder hidden
constexpr int An = 512;   // attention dim
constexpr int En = 2048;  // enc_dim

typedef __attribute__((ext_vector_type(8))) __bf16 bf16x8;
typedef __attribute__((ext_vector_type(4))) float floatx4;

// Split fp32 x into bf16 hi (truncated) + bf16 lo (RNE of exact residual).
// x ~= hi + lo with ~2^-17 relative error; a*b ~= ah*bh + ah*bl + al*bh.
__device__ __forceinline__ void split_f32(float x, unsigned short& hi, unsigned short& lo) {
  unsigned u = __float_as_uint(x);
  hi = (unsigned short)(u >> 16);                    // truncate -> exact residual
  float hif = __uint_as_float(u & 0xffff0000u);
  unsigned v = __float_as_uint(x - hif);             // exact subtraction
  v += 0x7fffu + ((v >> 16) & 1u);                   // RNE to bf16
  lo = (unsigned short)(v >> 16);
}

// ---------------------------------------------------------------------------
// K0: pre-split Wk [A,En] fp32 -> wkh/wkl bf16 (ushort) in workspace. 1M elems.
// ---------------------------------------------------------------------------
__global__ void wk_prep(const float* __restrict__ Wk,
                        unsigned short* __restrict__ wkh,
                        unsigned short* __restrict__ wkl) {
  const int lin = blockIdx.x * 256 + threadIdx.x;    // 0..262143 (float4 units)
  float4 v = ((const float4*)Wk)[lin];
  ushort4 h, l;
  split_f32(v.x, h.x, l.x); split_f32(v.y, h.y, l.y);
  split_f32(v.z, h.z, l.z); split_f32(v.w, h.w, l.w);
  ((ushort4*)wkh)[lin] = h;
  ((ushort4*)wkl)[lin] = l;
}

// ---------------------------------------------------------------------------
// K1: query[b,a] = relu(dec[b,:]·Wq[a,:] + bq[a]); also zeroes the energy
// accumulator (att slot) for K2's atomicAdds. grid (32,4) x 128.
// ---------------------------------------------------------------------------
__global__ void query_kernel(const float* __restrict__ dec,
                             const float* __restrict__ Wq,
                             const float* __restrict__ bq,
                             float* __restrict__ qbuf,
                             float* __restrict__ energy_zero) {
  __shared__ float sdec[Hn];
  const int b = blockIdx.x;
  // zero energy: 16384 threads x float4 = 65536 floats
  const int gl = (blockIdx.y * 32 + blockIdx.x) * 128 + threadIdx.x;
  ((float4*)energy_zero)[gl] = make_float4(0.f, 0.f, 0.f, 0.f);

  for (int i = threadIdx.x; i < Hn; i += blockDim.x) sdec[i] = dec[b * Hn + i];
  __syncthreads();
  const int a = blockIdx.y * 128 + threadIdx.x;
  const float* w = Wq + (size_t)a * Hn;
  float acc = 0.f;
  #pragma unroll 4
  for (int k = 0; k < Hn; k += 4) {
    float4 wv = *(const float4*)(w + k);
    acc = fmaf(wv.x, sdec[k + 0], acc);
    acc = fmaf(wv.y, sdec[k + 1], acc);
    acc = fmaf(wv.z, sdec[k + 2], acc);
    acc = fmaf(wv.w, sdec[k + 3], acc);
  }
  qbuf[b * An + a] = fmaxf(acc + bq[a], 0.f);
}

// ---------------------------------------------------------------------------
// K2: split-bf16 MFMA GEMM fused with relu+bias+dot(q) epilogue.
//   C[row,a] = sum_e enc[row,e]*Wk[a,e]   (both k-major -> B^T-style MFMA)
//   energy[row] += sum_a relu(C+bk[a]) * q[b,a]   (per-block partial, atomic)
// Block tile 128 rows x 128 a, BK=64; 4 waves in 2x2, wave tile 64x64
// (4x4 tiles of 16x16x32). LDS: XOR-swizzled 16B chunks, exactly 64 KB.
// 3 MFMAs per tile (hi*hi + hi*lo + lo*hi) ~= fp32 precision.
// ---------------------------------------------------------------------------
__global__ __launch_bounds__(256, 2)
void energy_kernel(const float* __restrict__ enc,
                   const unsigned short* __restrict__ wkh,
                   const unsigned short* __restrict__ wkl,
                   const float* __restrict__ bk,
                   const float* __restrict__ qbuf,
                   float* __restrict__ energy) {
  __shared__ unsigned short sAh[128 * 64], sAl[128 * 64];  // 16 KB each
  __shared__ unsigned short sBh[128 * 64], sBl[128 * 64];

  const int tid = threadIdx.x;
  const int lane = tid & 63;
  const int wid = tid >> 6;
  const int wr = wid >> 1, wc = wid & 1;   // wave grid 2x2
  const int lr = lane & 15, lq = lane >> 4;

  const int nblk = blockIdx.x & 3;         // n-blocks adjacent -> L3 catches enc reuse
  const long row_base = (long)(blockIdx.x >> 2) * 128;
  const int n_base = nblk * 128;
  const int b = (int)(row_base >> 11);     // 128-row chunks never cross a batch

  floatx4 acc[4][4];
  #pragma unroll
  for (int i = 0; i < 4; ++i)
    #pragma unroll
    for (int j = 0; j < 4; ++j) acc[i][j] = (floatx4){0.f, 0.f, 0.f, 0.f};

  for (int k0 = 0; k0 < En; k0 += 64) {
    // --- stage A: 128 rows x 64 k fp32, split -> bf16 hi/lo, swizzled chunks
    #pragma unroll
    for (int rep = 0; rep < 8; ++rep) {
      const int lin = tid + rep * 256;        // 0..2047 float4 units
      const int row = lin >> 4, e4 = lin & 15;
      float4 v = *(const float4*)(enc + (row_base + row) * En + k0 + e4 * 4);
      ushort4 h, l;
      split_f32(v.x, h.x, l.x); split_f32(v.y, h.y, l.y);
      split_f32(v.z, h.z, l.z); split_f32(v.w, h.w, l.w);
      const int chunk = e4 >> 1, half = e4 & 1;
      const int off = row * 64 + ((chunk ^ (row & 7)) << 3) + (half << 2);
      *(ushort4*)&sAh[off] = h;
      *(ushort4*)&sAl[off] = l;
    }
    // --- stage B: 128 a x 64 k bf16 hi/lo from workspace (16B chunks)
    #pragma unroll
    for (int rep = 0; rep < 4; ++rep) {
      const int lin = tid + rep * 256;        // 0..1023 chunk units
      const int a = lin >> 3, c = lin & 7;
      const size_t goff = (size_t)(n_base + a) * En + k0 + c * 8;
      uint4 h = *(const uint4*)(wkh + goff);
      uint4 l = *(const uint4*)(wkl + goff);
      const int off = a * 64 + ((c ^ (a & 7)) << 3);
      *(uint4*)&sBh[off] = h;
      *(uint4*)&sBl[off] = l;
    }
    __syncthreads();

    #pragma unroll
    for (int ks = 0; ks < 2; ++ks) {          // two K=32 steps
      const int cb = ks * 4 + lq;             // logical 8-bf16 chunk index
      bf16x8 ah[4], al[4], bh[4], bl[4];
      #pragma unroll
      for (int mt = 0; mt < 4; ++mt) {
        const int m = wr * 64 + mt * 16 + lr;
        const int off = m * 64 + ((cb ^ (m & 7)) << 3);
        ah[mt] = *(const bf16x8*)&sAh[off];
        al[mt] = *(const bf16x8*)&sAl[off];
      }
      #pragma unroll
      for (int nt = 0; nt < 4; ++nt) {
        const int n = wc * 64 + nt * 16 + lr;
        const int off = n * 64 + ((cb ^ (n & 7)) << 3);
        bh[nt] = *(const bf16x8*)&sBh[off];
        bl[nt] = *(const bf16x8*)&sBl[off];
      }
      #pragma unroll
      for (int mt = 0; mt < 4; ++mt)
        #pragma unroll
        for (int nt = 0; nt < 4; ++nt) {
          acc[mt][nt] = __builtin_amdgcn_mfma_f32_16x16x32_bf16(ah[mt], bl[nt], acc[mt][nt], 0, 0, 0);
          acc[mt][nt] = __builtin_amdgcn_mfma_f32_16x16x32_bf16(al[mt], bh[nt], acc[mt][nt], 0, 0, 0);
          acc[mt][nt] = __builtin_amdgcn_mfma_f32_16x16x32_bf16(ah[mt], bh[nt], acc[mt][nt], 0, 0, 0);
        }
    }
    __syncthreads();
  }

  // --- epilogue: relu(C + bk)*q, reduce over this block's 128 a-cols.
  // C/D layout: col = lane&15 (a), row = (lane>>4)*4 + reg (enc row). [m89]
  float bkv[4], qv[4];
  #pragma unroll
  for (int nt = 0; nt < 4; ++nt) {
    const int ncol = n_base + wc * 64 + nt * 16 + lr;
    bkv[nt] = bk[ncol];
    qv[nt] = qbuf[b * An + ncol];
  }
  #pragma unroll
  for (int mt = 0; mt < 4; ++mt) {
    #pragma unroll
    for (int r = 0; r < 4; ++r) {
      float s = 0.f;
      #pragma unroll
      for (int nt = 0; nt < 4; ++nt)
        s = fmaf(fmaxf(acc[mt][nt][r] + bkv[nt], 0.f), qv[nt], s);
      s += __shfl_xor(s, 1, 64);
      s += __shfl_xor(s, 2, 64);
      s += __shfl_xor(s, 4, 64);
      s += __shfl_xor(s, 8, 64);
      if (lr == 0) {
        const long row = row_base + wr * 64 + mt * 16 + lq * 4 + r;
        atomicAdd(&energy[row], s);
      }
    }
  }
}

// ---------------------------------------------------------------------------
// K3: in-place softmax over T with mask renorm; zeroes ctx for K4's atomics.
// ---------------------------------------------------------------------------
__global__ void softmax_kernel(float* __restrict__ att,
                               const float* __restrict__ mask,
                               float* __restrict__ ctx) {
  const int b = blockIdx.x;
  const int tid = threadIdx.x;
  const int lane = tid & 63;
  const int wave = tid >> 6;
  __shared__ float wred[4];

  for (int i = tid; i < En; i += 256) ctx[b * En + i] = 0.f;

  float e[8];
  float m = -INFINITY;
  #pragma unroll
  for (int i = 0; i < 8; ++i) {
    e[i] = att[b * Tn + tid + i * 256];
    m = fmaxf(m, e[i]);
  }
  #pragma unroll
  for (int off = 32; off > 0; off >>= 1) m = fmaxf(m, __shfl_xor(m, off, 64));
  if (lane == 0) wred[wave] = m;
  __syncthreads();
  m = fmaxf(fmaxf(wred[0], wred[1]), fmaxf(wred[2], wred[3]));
  __syncthreads();

  float p[8];
  float s = 0.f;
  #pragma unroll
  for (int i = 0; i < 8; ++i) {
    p[i] = expf(e[i] - m) * mask[b * Tn + tid + i * 256];
    s += p[i];
  }
  #pragma unroll
  for (int off = 32; off > 0; off >>= 1) s += __shfl_xor(s, off, 64);
  if (lane == 0) wred[wave] = s;
  __syncthreads();
  const float inv = 1.f / (wred[0] + wred[1] + wred[2] + wred[3]);
  #pragma unroll
  for (int i = 0; i < 8; ++i) att[b * Tn + tid + i * 256] = p[i] * inv;
}

// ---------------------------------------------------------------------------
// K4: context[b,e] += sum_t att[b,t]*enc[b,t,e]. grid 32b x 2e x 32tseg.
// Peaked-softmax skip: if all 64 weights in this t-segment are < 1e-9, the
// segment's contribution is < ~1e-6 -> skip the 256 KB read entirely.
// ---------------------------------------------------------------------------
__global__ void context_kernel(const float* __restrict__ enc,
                               const float* __restrict__ att,
                               float* __restrict__ ctx) {
  const int bid = blockIdx.x;
  const int b = bid >> 6;
  const int echunk = (bid >> 5) & 1;
  const int tseg = bid & 31;
  const int tid = threadIdx.x;
  const int lane = tid & 63;
  const int e0 = echunk * 1024 + tid * 4;
  const int t0 = tseg * 64;

  __shared__ float satt[64];
  if (tid < 64) satt[tid] = att[b * Tn + t0 + tid];
  __syncthreads();

  float wm = satt[lane];
  #pragma unroll
  for (int off = 32; off > 0; off >>= 1) wm = fmaxf(wm, __shfl_xor(wm, off, 64));
  if (wm < 1e-9f) return;   // negligible mass in this segment

  const float* base = enc + ((size_t)(b * Tn + t0)) * En + e0;
  float4 acc = make_float4(0.f, 0.f, 0.f, 0.f);
  #pragma unroll 8
  for (int t = 0; t < 64; ++t) {
    const float w = satt[t];
    float4 v = *(const float4*)(base + (size_t)t * En);
    acc.x = fmaf(w, v.x, acc.x);
    acc.y = fmaf(w, v.y, acc.y);
    acc.z = fmaf(w, v.z, acc.z);
    acc.w = fmaf(w, v.w, acc.w);
  }
  atomicAdd(&ctx[b * En + e0 + 0], acc.x);
  atomicAdd(&ctx[b * En + e0 + 1], acc.y);
  atomicAdd(&ctx[b * En + e0 + 2], acc.z);
  atomicAdd(&ctx[b * En + e0 + 3], acc.w);
}

// ---------------------------------------------------------------------------
extern "C" void kernel_launch(void* const* d_in, const int* in_sizes, int n_in,
                              void* d_out, int out_size, void* d_ws, size_t ws_size,
                              hipStream_t stream) {
  const float* enc  = (const float*)d_in[0];
  const float* dec  = (const float*)d_in[1];
  const float* mask = (const float*)d_in[2];
  const float* Wq   = (const float*)d_in[3];
  const float* bq   = (const float*)d_in[4];
  const float* Wk   = (const float*)d_in[5];
  const float* bk   = (const float*)d_in[6];

  float* out = (float*)d_out;
  float* att = out;                // output 0: attention [B,1,T]
  float* ctx = out + Bn * Tn;      // output 1: context  [B,En]

  // workspace: wk_hi (2 MB) | wk_lo (2 MB) | qbuf (64 KB)
  unsigned short* wkh = (unsigned short*)d_ws;
  unsigned short* wkl = wkh + (size_t)An * En;
  float* qbuf = (float*)(wkl + (size_t)An * En);

  wk_prep<<<(An * En) / (256 * 4), 256, 0, stream>>>(Wk, wkh, wkl);
  query_kernel<<<dim3(Bn, 4), 128, 0, stream>>>(dec, Wq, bq, qbuf, att);
  energy_kernel<<<(Bn * Tn / 128) * 4, 256, 0, stream>>>(enc, wkh, wkl, bk, qbuf, att);
  softmax_kernel<<<Bn, 256, 0, stream>>>(att, mask, ctx);
  context_kernel<<<Bn * 2 * 32, 256, 0, stream>>>(enc, att, ctx);
}

// Round 3
// 866.678 us; speedup vs baseline: 2.7130x; 1.3810x over previous
//
#include <hip/hip_runtime.h>
#include <math.h>

constexpr int Bn = 32;    // batch
constexpr int Tn = 2048;  // time
constexpr int Hn = 1024;  // decoder hidden
constexpr int An = 512;   // attention dim
constexpr int En = 2048;  // enc_dim

typedef __attribute__((ext_vector_type(8))) _Float16 halfx8;
typedef __attribute__((ext_vector_type(4))) float floatx4;

constexpr float WK_SCALE = 4096.0f;       // keeps Wk's fp16 residual in normal range
constexpr float WK_INV   = 1.0f / 4096.0f;

__device__ __forceinline__ unsigned short f2h_bits(float x) {
  _Float16 h = (_Float16)x;               // v_cvt_f16_f32, RNE
  return __builtin_bit_cast(unsigned short, h);
}

// async global->LDS, 16 B per lane; lds must be wave-uniform base (HW adds lane*16)
__device__ __forceinline__ void gload_lds16(const void* g, void* lds) {
  __builtin_amdgcn_global_load_lds(
      (const __attribute__((address_space(1))) unsigned int*)g,
      (__attribute__((address_space(3))) unsigned int*)lds, 16, 0, 0);
}

// ---------------------------------------------------------------------------
// K0: Wk [A,En] fp32 -> fp16 hi/lo, scaled by 4096. 1M elems.
// ---------------------------------------------------------------------------
__global__ void wk_prep(const float* __restrict__ Wk,
                        unsigned short* __restrict__ wkh,
                        unsigned short* __restrict__ wkl) {
  const int lin = blockIdx.x * 256 + threadIdx.x;   // float4 units, 0..262143
  float4 v = ((const float4*)Wk)[lin];
  ushort4 h, l;
  float s, hf;
  s = v.x * WK_SCALE; h.x = f2h_bits(s); hf = (float)__builtin_bit_cast(_Float16, h.x); l.x = f2h_bits(s - hf);
  s = v.y * WK_SCALE; h.y = f2h_bits(s); hf = (float)__builtin_bit_cast(_Float16, h.y); l.y = f2h_bits(s - hf);
  s = v.z * WK_SCALE; h.z = f2h_bits(s); hf = (float)__builtin_bit_cast(_Float16, h.z); l.z = f2h_bits(s - hf);
  s = v.w * WK_SCALE; h.w = f2h_bits(s); hf = (float)__builtin_bit_cast(_Float16, h.w); l.w = f2h_bits(s - hf);
  ((ushort4*)wkh)[lin] = h;
  ((ushort4*)wkl)[lin] = l;
}

// ---------------------------------------------------------------------------
// K1: query[b,a] = relu(dec[b,:]·Wq[a,:] + bq[a]); zeroes energy (att slot).
// ---------------------------------------------------------------------------
__global__ void query_kernel(const float* __restrict__ dec,
                             const float* __restrict__ Wq,
                             const float* __restrict__ bq,
                             float* __restrict__ qbuf,
                             float* __restrict__ energy_zero) {
  __shared__ float sdec[Hn];
  const int b = blockIdx.x;
  const int gl = (blockIdx.y * 32 + blockIdx.x) * 128 + threadIdx.x;
  ((float4*)energy_zero)[gl] = make_float4(0.f, 0.f, 0.f, 0.f);

  for (int i = threadIdx.x; i < Hn; i += blockDim.x) sdec[i] = dec[b * Hn + i];
  __syncthreads();
  const int a = blockIdx.y * 128 + threadIdx.x;
  const float* w = Wq + (size_t)a * Hn;
  float acc = 0.f;
  #pragma unroll 4
  for (int k = 0; k < Hn; k += 4) {
    float4 wv = *(const float4*)(w + k);
    acc = fmaf(wv.x, sdec[k + 0], acc);
    acc = fmaf(wv.y, sdec[k + 1], acc);
    acc = fmaf(wv.z, sdec[k + 2], acc);
    acc = fmaf(wv.w, sdec[k + 3], acc);
  }
  qbuf[b * An + a] = fmaxf(acc + bq[a], 0.f);
}

// ---------------------------------------------------------------------------
// K2: fp16 2-MFMA energy GEMM. C = enc_h16 · (Wk_hi + Wk_lo)^T (Wk scaled 4096)
// energy[row] += sum_a relu(C*(1/4096) + bk[a]) * q[b,a]
// Block 128 rows x 256 a, BK=64. 4 waves 2x2, wave tile 64x128 (4x8 of
// 16x16x32_f16, 2 MFMAs each). LDS: sA 16 KB + sB hi/lo 64 KB = 80 KB
// -> 2 blocks/CU. B staged via global_load_lds (swizzle on the global side).
// ---------------------------------------------------------------------------
__global__ __launch_bounds__(256, 2)
void energy_kernel(const float* __restrict__ enc,
                   const unsigned short* __restrict__ wkh,
                   const unsigned short* __restrict__ wkl,
                   const float* __restrict__ bk,
                   const float* __restrict__ qbuf,
                   float* __restrict__ energy) {
  __shared__ unsigned short sA[128 * 64];    // fp16 enc tile   (16 KB)
  __shared__ unsigned short sBh[256 * 64];   // fp16 Wk hi tile (32 KB)
  __shared__ unsigned short sBl[256 * 64];   // fp16 Wk lo tile (32 KB)

  const int tid = threadIdx.x;
  const int lane = tid & 63;
  const int wid = tid >> 6;
  const int wr = wid >> 1, wc = wid & 1;     // wave grid 2x2 (n-major inner)
  const int lr = lane & 15, lq = lane >> 4;

  const int nblk = blockIdx.x & 1;           // n-pairs adjacent -> L3 enc reuse
  const long row_base = (long)(blockIdx.x >> 1) * 128;
  const int n_base = nblk * 256;
  const int b = (int)(row_base >> 11);

  floatx4 acc[4][8];
  #pragma unroll
  for (int i = 0; i < 4; ++i)
    #pragma unroll
    for (int j = 0; j < 8; ++j) acc[i][j] = (floatx4){0.f, 0.f, 0.f, 0.f};

  for (int k0 = 0; k0 < En; k0 += 64) {
    // --- stage A: 128 rows x 64 k fp32 -> fp16, swizzled 16B chunks.
    // slot s of row holds k-chunk (s ^ (row&7)); here chunk c -> slot c^(row&7).
    #pragma unroll
    for (int rep = 0; rep < 8; ++rep) {
      const int lin = tid + rep * 256;           // 0..2047 float4 units
      const int row = lin >> 4, e4 = lin & 15;   // e4: float4 index (16 floats/row)
      float4 v = *(const float4*)(enc + (row_base + row) * En + k0 + e4 * 4);
      ushort4 h;
      h.x = f2h_bits(v.x); h.y = f2h_bits(v.y);
      h.z = f2h_bits(v.z); h.w = f2h_bits(v.w);
      const int chunk = e4 >> 1, half = e4 & 1;  // chunk = 8 fp16 = 16 B
      const int off = row * 64 + ((chunk ^ (row & 7)) << 3) + (half << 2);
      *(ushort4*)&sA[off] = h;
    }
    // --- stage B via global_load_lds: slot gidx holds chunk (gidx&7)^(a&7)
    // wave 'wid' stages gidx in [wid*512, wid*512+512), 8 iters of 64 lanes.
    #pragma unroll
    for (int it = 0; it < 8; ++it) {
      const int gidx = wid * 512 + it * 64 + lane;
      const int a = gidx >> 3;
      const int c = (gidx & 7) ^ (a & 7);
      const size_t goff = (size_t)(n_base + a) * En + k0 + c * 8;
      unsigned short* ldsb_h = &sBh[(wid * 512 + it * 64) * 8];
      unsigned short* ldsb_l = &sBl[(wid * 512 + it * 64) * 8];
      gload_lds16(wkh + goff, ldsb_h);
      gload_lds16(wkl + goff, ldsb_l);
    }
    __syncthreads();

    #pragma unroll
    for (int ks = 0; ks < 2; ++ks) {
      const int cb = ks * 4 + lq;                // k-chunk this quad consumes
      halfx8 ah[4];
      #pragma unroll
      for (int mt = 0; mt < 4; ++mt) {
        const int m = wr * 64 + mt * 16 + lr;
        ah[mt] = *(const halfx8*)&sA[m * 64 + ((cb ^ (m & 7)) << 3)];
      }
      #pragma unroll
      for (int ng = 0; ng < 2; ++ng) {           // split n-tiles to cap registers
        halfx8 bh[4], bl[4];
        #pragma unroll
        for (int nt = 0; nt < 4; ++nt) {
          const int n = wc * 128 + (ng * 4 + nt) * 16 + lr;
          const int off = n * 64 + ((cb ^ (n & 7)) << 3);
          bh[nt] = *(const halfx8*)&sBh[off];
          bl[nt] = *(const halfx8*)&sBl[off];
        }
        #pragma unroll
        for (int mt = 0; mt < 4; ++mt)
          #pragma unroll
          for (int nt = 0; nt < 4; ++nt) {
            acc[mt][ng * 4 + nt] = __builtin_amdgcn_mfma_f32_16x16x32_f16(ah[mt], bl[nt], acc[mt][ng * 4 + nt], 0, 0, 0);
            acc[mt][ng * 4 + nt] = __builtin_amdgcn_mfma_f32_16x16x32_f16(ah[mt], bh[nt], acc[mt][ng * 4 + nt], 0, 0, 0);
          }
      }
    }
    __syncthreads();
  }

  // --- epilogue: relu(C/4096 + bk)*q over 256 a-cols; C/D: col=lane&15,
  // row=(lane>>4)*4+reg  [m89]
  float bkv[8], qv[8];
  #pragma unroll
  for (int nt = 0; nt < 8; ++nt) {
    const int ncol = n_base + wc * 128 + nt * 16 + lr;
    bkv[nt] = bk[ncol];
    qv[nt] = qbuf[b * An + ncol];
  }
  #pragma unroll
  for (int mt = 0; mt < 4; ++mt) {
    #pragma unroll
    for (int r = 0; r < 4; ++r) {
      float s = 0.f;
      #pragma unroll
      for (int nt = 0; nt < 8; ++nt)
        s = fmaf(fmaxf(fmaf(acc[mt][nt][r], WK_INV, bkv[nt]), 0.f), qv[nt], s);
      s += __shfl_xor(s, 1, 64);
      s += __shfl_xor(s, 2, 64);
      s += __shfl_xor(s, 4, 64);
      s += __shfl_xor(s, 8, 64);
      if (lr == 0) {
        const long row = row_base + wr * 64 + mt * 16 + lq * 4 + r;
        atomicAdd(&energy[row], s);
      }
    }
  }
}

// ---------------------------------------------------------------------------
// K3: softmax over T with mask renorm + COMPACTION: block b owns batch b,
// appends (t, w) for w > 1e-7 to list[b] (dropped mass <= 2048e-7 -> err ~1e-3).
// ---------------------------------------------------------------------------
__global__ void softmax_kernel(float* __restrict__ att,
                               const float* __restrict__ mask,
                               uint2* __restrict__ list,
                               unsigned* __restrict__ cnt) {
  const int b = blockIdx.x;
  const int tid = threadIdx.x;
  const int lane = tid & 63;
  const int wave = tid >> 6;
  __shared__ float wred[4];
  __shared__ unsigned cnt_l;
  if (tid == 0) cnt_l = 0;

  float e[8];
  float m = -INFINITY;
  #pragma unroll
  for (int i = 0; i < 8; ++i) {
    e[i] = att[b * Tn + tid + i * 256];
    m = fmaxf(m, e[i]);
  }
  #pragma unroll
  for (int off = 32; off > 0; off >>= 1) m = fmaxf(m, __shfl_xor(m, off, 64));
  if (lane == 0) wred[wave] = m;
  __syncthreads();
  m = fmaxf(fmaxf(wred[0], wred[1]), fmaxf(wred[2], wred[3]));
  __syncthreads();

  float p[8];
  float s = 0.f;
  #pragma unroll
  for (int i = 0; i < 8; ++i) {
    p[i] = expf(e[i] - m) * mask[b * Tn + tid + i * 256];
    s += p[i];
  }
  #pragma unroll
  for (int off = 32; off > 0; off >>= 1) s += __shfl_xor(s, off, 64);
  if (lane == 0) wred[wave] = s;
  __syncthreads();
  const float inv = 1.f / (wred[0] + wred[1] + wred[2] + wred[3]);
  #pragma unroll
  for (int i = 0; i < 8; ++i) {
    const int t = tid + i * 256;
    const float w = p[i] * inv;
    att[b * Tn + t] = w;
    if (w > 1e-7f) {
      unsigned pos = atomicAdd(&cnt_l, 1u);
      list[b * Tn + pos] = make_uint2((unsigned)t, __float_as_uint(w));
    }
  }
  __syncthreads();
  if (tid == 0) cnt[b] = cnt_l;
}

// ---------------------------------------------------------------------------
// K4: context[b,e] = sum over compacted list of w * enc[b,t,e].
// grid (2 e-chunks, 32 b); block 256, float4/thread; block-owned -> plain store.
// ---------------------------------------------------------------------------
__global__ void context_kernel(const float* __restrict__ enc,
                               const uint2* __restrict__ list,
                               const unsigned* __restrict__ cnt,
                               float* __restrict__ ctx) {
  const int ec = blockIdx.x, b = blockIdx.y;
  const int tid = threadIdx.x;
  __shared__ uint2 slist[Tn];
  const int n = (int)cnt[b];
  for (int j = tid; j < n; j += 256) slist[j] = list[b * Tn + j];
  __syncthreads();

  const int e0 = ec * 1024 + tid * 4;
  const float* base = enc + (size_t)b * Tn * En + e0;
  float4 a0 = make_float4(0, 0, 0, 0), a1 = a0, a2 = a0, a3 = a0;
  int j = 0;
  for (; j + 4 <= n; j += 4) {
    uint2 p0 = slist[j], p1 = slist[j + 1], p2 = slist[j + 2], p3 = slist[j + 3];
    float4 v0 = *(const float4*)(base + (size_t)p0.x * En);
    float4 v1 = *(const float4*)(base + (size_t)p1.x * En);
    float4 v2 = *(const float4*)(base + (size_t)p2.x * En);
    float4 v3 = *(const float4*)(base + (size_t)p3.x * En);
    const float w0 = __uint_as_float(p0.y), w1 = __uint_as_float(p1.y);
    const float w2 = __uint_as_float(p2.y), w3 = __uint_as_float(p3.y);
    a0.x = fmaf(w0, v0.x, a0.x); a0.y = fmaf(w0, v0.y, a0.y); a0.z = fmaf(w0, v0.z, a0.z); a0.w = fmaf(w0, v0.w, a0.w);
    a1.x = fmaf(w1, v1.x, a1.x); a1.y = fmaf(w1, v1.y, a1.y); a1.z = fmaf(w1, v1.z, a1.z); a1.w = fmaf(w1, v1.w, a1.w);
    a2.x = fmaf(w2, v2.x, a2.x); a2.y = fmaf(w2, v2.y, a2.y); a2.z = fmaf(w2, v2.z, a2.z); a2.w = fmaf(w2, v2.w, a2.w);
    a3.x = fmaf(w3, v3.x, a3.x); a3.y = fmaf(w3, v3.y, a3.y); a3.z = fmaf(w3, v3.z, a3.z); a3.w = fmaf(w3, v3.w, a3.w);
  }
  for (; j < n; ++j) {
    uint2 p0 = slist[j];
    float4 v0 = *(const float4*)(base + (size_t)p0.x * En);
    const float w0 = __uint_as_float(p0.y);
    a0.x = fmaf(w0, v0.x, a0.x); a0.y = fmaf(w0, v0.y, a0.y); a0.z = fmaf(w0, v0.z, a0.z); a0.w = fmaf(w0, v0.w, a0.w);
  }
  a0.x += a1.x + a2.x + a3.x; a0.y += a1.y + a2.y + a3.y;
  a0.z += a1.z + a2.z + a3.z; a0.w += a1.w + a2.w + a3.w;
  *(float4*)(ctx + b * En + e0) = a0;
}

// ---------------------------------------------------------------------------
extern "C" void kernel_launch(void* const* d_in, const int* in_sizes, int n_in,
                              void* d_out, int out_size, void* d_ws, size_t ws_size,
                              hipStream_t stream) {
  const float* enc  = (const float*)d_in[0];
  const float* dec  = (const float*)d_in[1];
  const float* mask = (const float*)d_in[2];
  const float* Wq   = (const float*)d_in[3];
  const float* bq   = (const float*)d_in[4];
  const float* Wk   = (const float*)d_in[5];
  const float* bk   = (const float*)d_in[6];

  float* out = (float*)d_out;
  float* att = out;                // output 0: attention [B,1,T]
  float* ctx = out + Bn * Tn;      // output 1: context  [B,En]

  // ws layout: wkh (2MB) | wkl (2MB) | qbuf (64KB) | cnt (128B) | list (512KB)
  unsigned short* wkh = (unsigned short*)d_ws;
  unsigned short* wkl = wkh + (size_t)An * En;
  float* qbuf = (float*)(wkl + (size_t)An * En);
  unsigned* cnt = (unsigned*)(qbuf + Bn * An);
  uint2* list = (uint2*)(cnt + 32);

  wk_prep<<<(An * En) / (256 * 4), 256, 0, stream>>>(Wk, wkh, wkl);
  query_kernel<<<dim3(Bn, 4), 128, 0, stream>>>(dec, Wq, bq, qbuf, att);
  energy_kernel<<<(Bn * Tn / 128) * 2, 256, 0, stream>>>(enc, wkh, wkl, bk, qbuf, att);
  softmax_kernel<<<Bn, 256, 0, stream>>>(att, mask, list, cnt);
  context_kernel<<<dim3(2, Bn), 256, 0, stream>>>(enc, list, cnt, ctx);
}